// Round 2
// baseline (1155.691 us; speedup 1.0000x reference)
//
#include <hip/hip_runtime.h>
#include <hip/hip_bf16.h>

// GPT-2 fused causal attention, B=4 H=12 S=2048 D=64.
// Outputs: attn_output [B,H,S,D] then attn_weights [B,H,S,S], flat in d_out.
// DTYPE-ADAPTIVE: detects fp32 vs bf16 input by testing whether the low u16
// of the first 32 words decodes as a sane bf16 (bf16 data -> yes; fp32
// mantissa junk -> ~20% only). Same flag selects output store width.
// Core compute is bf16 MFMA either way (fp32 inputs are converted on load).
// One workgroup (4 waves) per (b*h, 64-row q tile); two passes over k-tiles:
//   phase 1: online softmax stats (m,l);  phase 2: weights + O = P V.
// PV is operand-swapped (O^T = V^T P^T) to avoid an LDS transpose of V.
// Correctness-first round: plain VGPR staging (no global_load_lds), barriers
// instead of hand waitcnt.

#define S_LEN 2048
#define DH    64
#define NHD   12
#define H3    2304   // 3*768
#define QT    64
#define KTILE 64
#define NT    32     // S_LEN / KTILE
#define PSTR  72     // p_lds row stride: 144B rows, 16B aligned
#define OSZ   (4 * NHD * S_LEN * DH)   // attn_output element count

typedef __attribute__((ext_vector_type(8))) short short8;
typedef __attribute__((ext_vector_type(4))) float f32x4;

__device__ __forceinline__ short bfc(float x) {
  return (short)__builtin_bit_cast(unsigned short, __float2bfloat16(x));
}
__device__ __forceinline__ float b2f(unsigned short u) {
  return __builtin_bit_cast(float, (unsigned int)u << 16);
}
// load 8 consecutive fp32, round to bf16, pack
__device__ __forceinline__ short8 cvt8(const float* p) {
  const float4 a = *(const float4*)p;
  const float4 b = *(const float4*)(p + 4);
  short8 r;
  r[0] = bfc(a.x); r[1] = bfc(a.y); r[2] = bfc(a.z); r[3] = bfc(a.w);
  r[4] = bfc(b.x); r[5] = bfc(b.y); r[6] = bfc(b.z); r[7] = bfc(b.w);
  return r;
}

__global__ __launch_bounds__(256)
void attn_fused(const void* __restrict__ xv, void* __restrict__ ov)
{
  __shared__ __align__(16) unsigned short k_lds[KTILE * DH];   // [key][d]
  __shared__ __align__(16) unsigned short v_lds[KTILE * DH];   // [key][d]
  __shared__ __align__(16) unsigned short p_lds[QT * PSTR];    // [q][key] padded

  const int tid  = threadIdx.x;
  const int wave = tid >> 6;
  const int lane = tid & 63;
  const int quad = lane >> 4;
  const int l16  = lane & 15;

  // ---- input dtype detection: low u16 of first 32 words sane as bf16? ----
  const unsigned int* xw = (const unsigned int*)xv;
  int cnt = 0;
  #pragma unroll
  for (int j = 0; j < 32; ++j) {
    const unsigned e = (xw[j] >> 7) & 0xFFu;   // bf16 exponent of low half
    cnt += (e >= 100u && e <= 150u) ? 1 : 0;
  }
  const bool isf32 = (cnt < 24);   // bf16 data: 32/32 sane; fp32: ~6/32

  const unsigned short* xh = (const unsigned short*)xv;
  const float*          xf = (const float*)xv;

  const int qb = (NT - 1) - blockIdx.x;   // big q-tiles first
  const int bh = blockIdx.y;
  const int b  = bh / NHD;
  const int h  = bh - b * NHD;
  const int q_base = qb * QT;

  // ---- Q A-fragments: A[m=l16][k=quad*8+j] ----
  const int qrow = q_base + wave * 16 + l16;
  const size_t qoff = (size_t)(b * S_LEN + qrow) * H3 + h * DH + quad * 8;
  short8 qa0, qa1;
  if (isf32) { qa0 = cvt8(xf + qoff); qa1 = cvt8(xf + qoff + 32); }
  else       { qa0 = *(const short8*)(xh + qoff);
               qa1 = *(const short8*)(xh + qoff + 32); }

  // ---- staging geometry: 512 chunks of 8 bf16 elems, 2 per thread ----
  const int c0 = tid,     c1 = tid + 256;
  const int r0 = c0 >> 3, o0 = (c0 & 7) * 8;
  const int r1 = c1 >> 3, o1 = (c1 & 7) * 8;
  const size_t koff0 = ((size_t)b * S_LEN + r0) * H3 + 768 + h * DH + o0;
  const size_t koff1 = ((size_t)b * S_LEN + r1) * H3 + 768 + h * DH + o1;

  const int qg0 = q_base + wave * 16 + quad * 4;

  auto compute_scores = [&](int kt, float (&sc)[4][4]) {
    #pragma unroll
    for (int n16 = 0; n16 < 4; ++n16) {
      const unsigned short* kr = &k_lds[(n16 * 16 + l16) * DH + quad * 8];
      const short8 kb0 = *(const short8*)kr;        // B[k=d][n=key]
      const short8 kb1 = *(const short8*)(kr + 32);
      f32x4 acc = {0.f, 0.f, 0.f, 0.f};
      acc = __builtin_amdgcn_mfma_f32_16x16x32_bf16(qa0, kb0, acc, 0, 0, 0);
      acc = __builtin_amdgcn_mfma_f32_16x16x32_bf16(qa1, kb1, acc, 0, 0, 0);
      const int keyg = kt * KTILE + n16 * 16 + l16;
      #pragma unroll
      for (int r = 0; r < 4; ++r)
        sc[n16][r] = (keyg <= qg0 + r) ? acc[r] * 0.125f : -1e30f;
    }
  };

  float m_r[4], l_r[4];
  #pragma unroll
  for (int r = 0; r < 4; ++r) { m_r[r] = -1e30f; l_r[r] = 0.f; }

  // ================= phase 1: softmax stats =================
  for (int kt = 0; kt <= qb; ++kt) {
    __syncthreads();
    const size_t t = (size_t)kt * KTILE * H3;
    short8 s0, s1;
    if (isf32) { s0 = cvt8(xf + koff0 + t); s1 = cvt8(xf + koff1 + t); }
    else       { s0 = *(const short8*)(xh + koff0 + t);
                 s1 = *(const short8*)(xh + koff1 + t); }
    *(short8*)&k_lds[c0 * 8] = s0;
    *(short8*)&k_lds[c1 * 8] = s1;
    __syncthreads();

    float sc[4][4];
    compute_scores(kt, sc);

    #pragma unroll
    for (int r = 0; r < 4; ++r) {
      float tmax = fmaxf(fmaxf(sc[0][r], sc[1][r]), fmaxf(sc[2][r], sc[3][r]));
      #pragma unroll
      for (int sh = 1; sh < 16; sh <<= 1)
        tmax = fmaxf(tmax, __shfl_xor(tmax, sh, 64));
      const float mn = fmaxf(m_r[r], tmax);
      float ps = __expf(sc[0][r] - mn) + __expf(sc[1][r] - mn)
               + __expf(sc[2][r] - mn) + __expf(sc[3][r] - mn);
      #pragma unroll
      for (int sh = 1; sh < 16; sh <<= 1)
        ps += __shfl_xor(ps, sh, 64);
      l_r[r] = l_r[r] * __expf(m_r[r] - mn) + ps;
      m_r[r] = mn;
    }
  }

  float invl[4];
  #pragma unroll
  for (int r = 0; r < 4; ++r) invl[r] = 1.f / l_r[r];

  // ================= phase 2: weights + O =================
  f32x4 o_acc[4];
  #pragma unroll
  for (int m16 = 0; m16 < 4; ++m16) o_acc[m16] = (f32x4){0.f, 0.f, 0.f, 0.f};

  const size_t wbase = ((size_t)bh * S_LEN + q_base + wave * 16) * S_LEN;
  float*          wrF = (float*)ov + OSZ + wbase;
  unsigned short* wrH = (unsigned short*)ov + OSZ + wbase;

  for (int kt = 0; kt <= qb; ++kt) {
    __syncthreads();
    const size_t t = (size_t)kt * KTILE * H3;
    short8 s0, s1, u0, u1;
    if (isf32) {
      s0 = cvt8(xf + koff0 + t);       s1 = cvt8(xf + koff1 + t);
      u0 = cvt8(xf + koff0 + t + 768); u1 = cvt8(xf + koff1 + t + 768);
    } else {
      s0 = *(const short8*)(xh + koff0 + t);
      s1 = *(const short8*)(xh + koff1 + t);
      u0 = *(const short8*)(xh + koff0 + t + 768);
      u1 = *(const short8*)(xh + koff1 + t + 768);
    }
    *(short8*)&k_lds[c0 * 8] = s0;  *(short8*)&k_lds[c1 * 8] = s1;
    *(short8*)&v_lds[c0 * 8] = u0;  *(short8*)&v_lds[c1 * 8] = u1;
    __syncthreads();

    float sc[4][4];
    compute_scores(kt, sc);

    // normalized probabilities -> bf16 -> p_lds (wave-private rows)
    #pragma unroll
    for (int n16 = 0; n16 < 4; ++n16) {
      #pragma unroll
      for (int r = 0; r < 4; ++r) {
        const float p = __expf(sc[n16][r] - m_r[r]) * invl[r];  // masked -> 0
        p_lds[(wave * 16 + quad * 4 + r) * PSTR + n16 * 16 + l16] =
            (unsigned short)bfc(p);
      }
    }
    __syncthreads();   // order p writes before reads (conservative)

    // B-frags of P^T: B[k=key][n=q]
    const unsigned short* pr = &p_lds[(wave * 16 + l16) * PSTR + quad * 8];
    const short8 pb0 = *(const short8*)pr;
    const short8 pb1 = *(const short8*)(pr + 32);

    // O^T += V^T P^T : A[m=d][k=key]
    #pragma unroll
    for (int m16 = 0; m16 < 4; ++m16) {
      short8 va0, va1;
      #pragma unroll
      for (int j = 0; j < 8; ++j) {
        va0[j] = (short)v_lds[(quad * 8 + j) * DH + m16 * 16 + l16];
        va1[j] = (short)v_lds[(quad * 8 + j + 32) * DH + m16 * 16 + l16];
      }
      o_acc[m16] = __builtin_amdgcn_mfma_f32_16x16x32_bf16(va0, pb0, o_acc[m16], 0, 0, 0);
      o_acc[m16] = __builtin_amdgcn_mfma_f32_16x16x32_bf16(va1, pb1, o_acc[m16], 0, 0, 0);
    }

    // weights tile store: 16 rows x 64 keys per wave
    #pragma unroll
    for (int i = 0; i < 2; ++i) {
      const int c = lane + i * 64;
      const int row = c >> 3, col8 = c & 7;
      const short8 pw = *(const short8*)&p_lds[(wave * 16 + row) * PSTR + col8 * 8];
      if (isf32) {
        float* d = wrF + (size_t)row * S_LEN + kt * KTILE + col8 * 8;
        *(float4*)d       = make_float4(b2f(pw[0]), b2f(pw[1]), b2f(pw[2]), b2f(pw[3]));
        *(float4*)(d + 4) = make_float4(b2f(pw[4]), b2f(pw[5]), b2f(pw[6]), b2f(pw[7]));
      } else {
        *(short8*)&wrH[(size_t)row * S_LEN + kt * KTILE + col8 * 8] = pw;
      }
    }
  }

  // ---- zero-fill fully-masked upper-triangle weight tiles ----
  for (int kt = qb + 1; kt < NT; ++kt) {
    #pragma unroll
    for (int i = 0; i < 2; ++i) {
      const int c = lane + i * 64;
      const int row = c >> 3, col8 = c & 7;
      if (isf32) {
        float* d = wrF + (size_t)row * S_LEN + kt * KTILE + col8 * 8;
        *(float4*)d       = make_float4(0.f, 0.f, 0.f, 0.f);
        *(float4*)(d + 4) = make_float4(0.f, 0.f, 0.f, 0.f);
      } else {
        const short8 zz = {0, 0, 0, 0, 0, 0, 0, 0};
        *(short8*)&wrH[(size_t)row * S_LEN + kt * KTILE + col8 * 8] = zz;
      }
    }
  }

  // ---- store O: D=O^T -> q = l16, d = m16*16 + quad*4 + r ----
  const size_t obase = ((size_t)bh * S_LEN + q_base + wave * 16 + l16) * DH;
  #pragma unroll
  for (int m16 = 0; m16 < 4; ++m16) {
    #pragma unroll
    for (int r = 0; r < 4; ++r) {
      const int d = m16 * 16 + quad * 4 + r;
      if (isf32) ((float*)ov)[obase + d] = o_acc[m16][r];
      else ((unsigned short*)ov)[obase + d] = (unsigned short)bfc(o_acc[m16][r]);
    }
  }
}

extern "C" void kernel_launch(void* const* d_in, const int* in_sizes, int n_in,
                              void* d_out, int out_size, void* d_ws, size_t ws_size,
                              hipStream_t stream) {
  // d_in[0]: x [4,2048,2304] (fp32 or bf16 -- detected on device)
  // d_in[1]: causal mask (known tril(2048)) -- not read.
  dim3 grid(NT, 4 * NHD);
  attn_fused<<<grid, 256, 0, stream>>>(d_in[0], d_out);
}